// Round 2
// baseline (1200.751 us; speedup 1.0000x reference)
//
#include <hip/hip_runtime.h>

// GraphConstruction: x[1,1024,1024] fp32 -> A[4096,4096] in {0,1} fp32.
// patches[n,r,k] = x[h,w], h = (n&15)*64 + (r>>2)*16 + (n>>8),
//                          w = (r&3)*256 + k*16 + ((n>>4)&15)
// LOCKED NUMERICS (R6..R13, absmax 0):
//   sq[n,k]: acc = p0^2; acc = acc + fl(p_r^2), r ascending (plain adds)
//   G: acc = fmaf(a_r, b_r, acc), r ascending;  d2 = fmaf(-2,G,fl(si+sj))
//   decision: all_k (d2 <= 49.0f) == !any_k (d2 > 49.0f) -> per-cell FAIL
//   BIT instead of running fp max. A bit-exactly symmetric -> mirror stores.
// R15 = R14 (128x128 block, 8x8/thread) with ALL per-thread arrays replaced
//   by NAMED scalars/float4s. R14 post-mortem: VGPR_Count=84 + WRITE_SIZE
//   1.6GB + VALUBusy 8% -> hipcc demoted d[8][8]/a[8]/si[8] to scratch
//   (SROA failure, rule #20), 943us. Named vars (d0A..d7B, a0..a7) have no
//   alloca -> nothing to spill. Peak live ~130 VGPR < 168 cap at 3 waves/EU.
//   LDS economics unchanged: 1.0 B/FMA (half of R13) -> ~50us LDS floor.
//   Swizzle: stride 9 float4, ch = c ^ swzrow(row); a-reads 4 distinct
//   groups, b-reads 2-way (free, m136), stage writes ~2-way.

#define NPATCH 4096
#define BT 128
#define NT (NPATCH / BT)   // 32 -> 528 lower-triangle blocks
#define NPH 8
#define KC 2
#define RSTRIDE 9          // float4 per row (8 data chunks + 1 pad)

__device__ __forceinline__ int swzrow(int row) {
    return ((row >> 2) + (row >> 5)) & 7;
}

// d{u}A holds cols v=0..3, d{u}B cols v=4..7; chain = fmaf r ascending.
#define FMA4(dst, av, bv)              \
    dst = fmaf(av.x, bv.x, dst);       \
    dst = fmaf(av.y, bv.y, dst);       \
    dst = fmaf(av.z, bv.z, dst);       \
    dst = fmaf(av.w, bv.w, dst);

#define LDA(u)                                                                 \
    const float4 a##u = Si[(ty * 8 + u) * RSTRIDE +                            \
                           (c ^ ((((ty * 8 + u) >> 2) + ((ty * 8 + u) >> 5)) & 7))];

#define COL(v, comp)                                                           \
    {                                                                          \
        const int row_ = tx * 8 + v;                                           \
        const float4 b_ =                                                      \
            Sj[row_ * RSTRIDE + (c ^ (((row_ >> 2) + (row_ >> 5)) & 7))];      \
        FMA4(d0##comp, a0, b_)                                                 \
        FMA4(d1##comp, a1, b_)                                                 \
        FMA4(d2##comp, a2, b_)                                                 \
        FMA4(d3##comp, a3, b_)                                                 \
        FMA4(d4##comp, a4, b_)                                                 \
        FMA4(d5##comp, a5, b_)                                                 \
        FMA4(d6##comp, a6, b_)                                                 \
        FMA4(d7##comp, a7, b_)                                                 \
    }

#define CELL(dcomp, siv, sjv, fw, bit)                                         \
    {                                                                          \
        const float s_ = (siv) + (sjv);          /* fl(si+sj) */               \
        const float d2_ = fmaf(-2.0f, dcomp, s_); /* fl(s-2G) */               \
        fw |= (d2_ > 49.0f ? 1u : 0u) << (bit);                                \
    }

#define EPIROW(u, siv, fw, base)                                               \
    CELL(d##u##A.x, siv, sj0.x, fw, (base) + 0)                                \
    CELL(d##u##A.y, siv, sj0.y, fw, (base) + 1)                                \
    CELL(d##u##A.z, siv, sj0.z, fw, (base) + 2)                                \
    CELL(d##u##A.w, siv, sj0.w, fw, (base) + 3)                                \
    CELL(d##u##B.x, siv, sj1.x, fw, (base) + 4)                                \
    CELL(d##u##B.y, siv, sj1.y, fw, (base) + 5)                                \
    CELL(d##u##B.z, siv, sj1.z, fw, (base) + 6)                                \
    CELL(d##u##B.w, siv, sj1.w, fw, (base) + 7)

__global__ __launch_bounds__(256, 3) void adj_kernel(const float* __restrict__ x,
                                                     float* __restrict__ A) {
#pragma clang fp contract(off)
    __shared__ float4 Si[BT * RSTRIDE];
    __shared__ float4 Sj[BT * RSTRIDE];
    __shared__ float sqs[2][KC][BT];

    // linear -> lower-triangle (bi >= bj)
    int t = blockIdx.x;
    int bi = (int)((sqrtf(8.0f * (float)t + 1.0f) - 1.0f) * 0.5f);
    while ((bi + 1) * (bi + 2) / 2 <= t) ++bi;
    while (bi * (bi + 1) / 2 > t) --bi;
    int bj = t - bi * (bi + 1) / 2;

    const int i0 = bi * BT;
    const int j0 = bj * BT;
    const int tid = threadIdx.x;
    const int tx = tid & 15;       // j-cols tx*8..+7
    const int ty = tid >> 4;       // i-rows ty*8..+7

    unsigned fail0 = 0u, fail1 = 0u;   // bit u*8+v (u<4) / (u-4)*8+v

    for (int kp = 0; kp < NPH; ++kp) {
        __syncthreads();
        // ---- stage: 2048 float4 loads, 8/thread; each covers 4 rows ----
#pragma unroll
        for (int l = 0; l < 8; ++l) {
            int gid = l * 256 + tid;
            int side = gid >> 10;
            int q = gid & 1023;            // m4(4) | r(4) | kl(1) | g(1)
            int g = q & 1;
            int kl = (q >> 1) & 1;
            int r = (q >> 2) & 15;
            int m4 = q >> 6;
            int k = kp * KC + kl;
            int bt = side ? bj : bi;
            int h = m4 * 64 + (r >> 2) * 16 + (bt >> 1);
            int w0 = (r & 3) * 256 + k * 16 + 8 * (bt & 1) + 4 * g;
            float4 v = *(const float4*)&x[h * 1024 + w0];
            int c = (kl << 2) | (r >> 2);
            int e = r & 3;
            float* Sb = side ? (float*)Sj : (float*)Si;
#pragma unroll
            for (int dd = 0; dd < 4; ++dd) {   // elem dd -> row (4g+dd)*16+m4
                float val = (dd == 0) ? v.x : (dd == 1) ? v.y : (dd == 2) ? v.z : v.w;
                int row = (4 * g + dd) * 16 + m4;
                int ch = c ^ swzrow(row);
                Sb[(row * RSTRIDE + ch) * 4 + e] = val;
            }
        }
        __syncthreads();
        // ---- per-column sq: plain adds, r ascending (2 values/thread) ----
#pragma unroll
        for (int s = 0; s < 2; ++s) {
            int idx = s * 256 + tid;
            int side = idx >> 8;
            int kl = (idx >> 7) & 1;
            int row = idx & 127;
            const float4* Sb = (side ? Sj : Si) + row * RSTRIDE;
            int swz = swzrow(row);
            float acc;
            {
                float4 v = Sb[(kl * 4) ^ swz];
                acc = v.x * v.x;
                float t1 = v.y * v.y; acc = acc + t1;
                float t2 = v.z * v.z; acc = acc + t2;
                float t3 = v.w * v.w; acc = acc + t3;
            }
#pragma unroll
            for (int rc = 1; rc < 4; ++rc) {
                float4 v = Sb[(kl * 4 + rc) ^ swz];
                float t0 = v.x * v.x; acc = acc + t0;
                float t1 = v.y * v.y; acc = acc + t1;
                float t2 = v.z * v.z; acc = acc + t2;
                float t3 = v.w * v.w; acc = acc + t3;
            }
            sqs[side][kl][row] = acc;
        }
        __syncthreads();
        // ---- compute: 8x8 cells via named float4 accumulators ----
#pragma unroll
        for (int kl = 0; kl < KC; ++kl) {
            float4 d0A = {0.f, 0.f, 0.f, 0.f}, d0B = {0.f, 0.f, 0.f, 0.f};
            float4 d1A = {0.f, 0.f, 0.f, 0.f}, d1B = {0.f, 0.f, 0.f, 0.f};
            float4 d2A = {0.f, 0.f, 0.f, 0.f}, d2B = {0.f, 0.f, 0.f, 0.f};
            float4 d3A = {0.f, 0.f, 0.f, 0.f}, d3B = {0.f, 0.f, 0.f, 0.f};
            float4 d4A = {0.f, 0.f, 0.f, 0.f}, d4B = {0.f, 0.f, 0.f, 0.f};
            float4 d5A = {0.f, 0.f, 0.f, 0.f}, d5B = {0.f, 0.f, 0.f, 0.f};
            float4 d6A = {0.f, 0.f, 0.f, 0.f}, d6B = {0.f, 0.f, 0.f, 0.f};
            float4 d7A = {0.f, 0.f, 0.f, 0.f}, d7B = {0.f, 0.f, 0.f, 0.f};
#pragma unroll
            for (int rc = 0; rc < 4; ++rc) {
                const int c = kl * 4 + rc;
                LDA(0) LDA(1) LDA(2) LDA(3) LDA(4) LDA(5) LDA(6) LDA(7)
                COL(0, A.x)
                COL(1, A.y)
                COL(2, A.z)
                COL(3, A.w)
                COL(4, B.x)
                COL(5, B.y)
                COL(6, B.z)
                COL(7, B.w)
            }
            const float4 si0 = *(const float4*)&sqs[0][kl][ty * 8];
            const float4 si1 = *(const float4*)&sqs[0][kl][ty * 8 + 4];
            const float4 sj0 = *(const float4*)&sqs[1][kl][tx * 8];
            const float4 sj1 = *(const float4*)&sqs[1][kl][tx * 8 + 4];
            EPIROW(0, si0.x, fail0, 0)
            EPIROW(1, si0.y, fail0, 8)
            EPIROW(2, si0.z, fail0, 16)
            EPIROW(3, si0.w, fail0, 24)
            EPIROW(4, si1.x, fail1, 0)
            EPIROW(5, si1.y, fail1, 8)
            EPIROW(6, si1.z, fail1, 16)
            EPIROW(7, si1.w, fail1, 24)
        }
    }

    // ---- stores: direct + mirrored (A exactly symmetric) ----
#pragma unroll
    for (int u = 0; u < 8; ++u) {
        unsigned m8 = ((u < 4) ? (fail0 >> (u * 8)) : (fail1 >> ((u - 4) * 8))) & 0xffu;
        float4 o0, o1;
        o0.x = (m8 & 1u)   ? 0.0f : 1.0f;
        o0.y = (m8 & 2u)   ? 0.0f : 1.0f;
        o0.z = (m8 & 4u)   ? 0.0f : 1.0f;
        o0.w = (m8 & 8u)   ? 0.0f : 1.0f;
        o1.x = (m8 & 16u)  ? 0.0f : 1.0f;
        o1.y = (m8 & 32u)  ? 0.0f : 1.0f;
        o1.z = (m8 & 64u)  ? 0.0f : 1.0f;
        o1.w = (m8 & 128u) ? 0.0f : 1.0f;
        size_t base = (size_t)(i0 + ty * 8 + u) * NPATCH + j0 + tx * 8;
        *(float4*)&A[base] = o0;
        *(float4*)&A[base + 4] = o1;
    }
    if (bi != bj) {
#pragma unroll
        for (int v = 0; v < 8; ++v) {
            float4 o0, o1;
            o0.x = ((fail0 >> (0 * 8 + v)) & 1u) ? 0.0f : 1.0f;
            o0.y = ((fail0 >> (1 * 8 + v)) & 1u) ? 0.0f : 1.0f;
            o0.z = ((fail0 >> (2 * 8 + v)) & 1u) ? 0.0f : 1.0f;
            o0.w = ((fail0 >> (3 * 8 + v)) & 1u) ? 0.0f : 1.0f;
            o1.x = ((fail1 >> (0 * 8 + v)) & 1u) ? 0.0f : 1.0f;
            o1.y = ((fail1 >> (1 * 8 + v)) & 1u) ? 0.0f : 1.0f;
            o1.z = ((fail1 >> (2 * 8 + v)) & 1u) ? 0.0f : 1.0f;
            o1.w = ((fail1 >> (3 * 8 + v)) & 1u) ? 0.0f : 1.0f;
            size_t base = (size_t)(j0 + tx * 8 + v) * NPATCH + i0 + ty * 8;
            *(float4*)&A[base] = o0;
            *(float4*)&A[base + 4] = o1;
        }
    }
}

extern "C" void kernel_launch(void* const* d_in, const int* in_sizes, int n_in,
                              void* d_out, int out_size, void* d_ws, size_t ws_size,
                              hipStream_t stream) {
    const float* x = (const float*)d_in[0];
    float* A = (float*)d_out;
    (void)d_ws; (void)ws_size;

    const int nblk = NT * (NT + 1) / 2;  // 528
    adj_kernel<<<nblk, 256, 0, stream>>>(x, A);
}

// Round 3
// 613.039 us; speedup vs baseline: 1.9587x; 1.9587x over previous
//
#include <hip/hip_runtime.h>

// GraphConstruction: x[1,1024,1024] fp32 -> A[4096,4096] in {0,1} fp32.
// patches[n,r,k] = x[h,w], h = (n&15)*64 + (r>>2)*16 + (n>>8),
//                          w = (r&3)*256 + k*16 + ((n>>4)&15)
// LOCKED NUMERICS (R6..R15, absmax 0):
//   sq[n,k]: acc = p0^2; acc = acc + fl(p_r^2), r ascending (plain adds)
//   G: acc = fmaf(a_r, b_r, acc), r ascending;  d2 = fmaf(-2,G,fl(si+sj))
//   decision: all_k (d2 <= 49.0f) == !any_k (d2 > 49.0f) -> per-cell FAIL
//   BIT instead of running fp max. A bit-exactly symmetric -> mirror stores.
// R16 = R15 (128x128 block, 8x8/thread, named float4 accumulators) with the
//   occupancy attribute pinned: amdgpu_waves_per_eu(2,2).
//   R14/R15 post-mortem: VGPR_Count was EXACTLY 84 = floor(512/6) in both,
//   independent of source structure (array vs named SSA) -> not an alloca/
//   SROA failure but the backend TARGETING 6 waves/EU and spilling the
//   ~130-reg live set to scratch (FETCH/WRITE ~1-2 GB, VALUBusy 7%).
//   __launch_bounds__(256,3) only sets a MINIMUM (cap 168); waves_per_eu(2,2)
//   pins target=2 waves/EU -> 256-VGPR budget -> no spill incentive.
//   2 blocks/CU is exactly right: grid 528 = 2.06 blocks/CU, LDS 38.9KB
//   allows 4. R15 already proved these numerics absmax=0.
//   LDS economics: 1.0 B/FMA (half of R13) -> ~50us LDS floor; FMA floor
//   27.7us; predicted 65-85us.

#define NPATCH 4096
#define BT 128
#define NT (NPATCH / BT)   // 32 -> 528 lower-triangle blocks
#define NPH 8
#define KC 2
#define RSTRIDE 9          // float4 per row (8 data chunks + 1 pad)

__device__ __forceinline__ int swzrow(int row) {
    return ((row >> 2) + (row >> 5)) & 7;
}

// d{u}A holds cols v=0..3, d{u}B cols v=4..7; chain = fmaf r ascending.
#define FMA4(dst, av, bv)              \
    dst = fmaf(av.x, bv.x, dst);       \
    dst = fmaf(av.y, bv.y, dst);       \
    dst = fmaf(av.z, bv.z, dst);       \
    dst = fmaf(av.w, bv.w, dst);

#define LDA(u)                                                                 \
    const float4 a##u = Si[(ty * 8 + u) * RSTRIDE +                            \
                           (c ^ ((((ty * 8 + u) >> 2) + ((ty * 8 + u) >> 5)) & 7))];

#define COL(v, comp)                                                           \
    {                                                                          \
        const int row_ = tx * 8 + v;                                           \
        const float4 b_ =                                                      \
            Sj[row_ * RSTRIDE + (c ^ (((row_ >> 2) + (row_ >> 5)) & 7))];      \
        FMA4(d0##comp, a0, b_)                                                 \
        FMA4(d1##comp, a1, b_)                                                 \
        FMA4(d2##comp, a2, b_)                                                 \
        FMA4(d3##comp, a3, b_)                                                 \
        FMA4(d4##comp, a4, b_)                                                 \
        FMA4(d5##comp, a5, b_)                                                 \
        FMA4(d6##comp, a6, b_)                                                 \
        FMA4(d7##comp, a7, b_)                                                 \
    }

#define CELL(dcomp, siv, sjv, fw, bit)                                         \
    {                                                                          \
        const float s_ = (siv) + (sjv);          /* fl(si+sj) */               \
        const float d2_ = fmaf(-2.0f, dcomp, s_); /* fl(s-2G) */               \
        fw |= (d2_ > 49.0f ? 1u : 0u) << (bit);                                \
    }

#define EPIROW(u, siv, fw, base)                                               \
    CELL(d##u##A.x, siv, sj0.x, fw, (base) + 0)                                \
    CELL(d##u##A.y, siv, sj0.y, fw, (base) + 1)                                \
    CELL(d##u##A.z, siv, sj0.z, fw, (base) + 2)                                \
    CELL(d##u##A.w, siv, sj0.w, fw, (base) + 3)                                \
    CELL(d##u##B.x, siv, sj1.x, fw, (base) + 4)                                \
    CELL(d##u##B.y, siv, sj1.y, fw, (base) + 5)                                \
    CELL(d##u##B.z, siv, sj1.z, fw, (base) + 6)                                \
    CELL(d##u##B.w, siv, sj1.w, fw, (base) + 7)

__global__ __launch_bounds__(256)
__attribute__((amdgpu_waves_per_eu(2, 2)))
void adj_kernel(const float* __restrict__ x, float* __restrict__ A) {
#pragma clang fp contract(off)
    __shared__ float4 Si[BT * RSTRIDE];
    __shared__ float4 Sj[BT * RSTRIDE];
    __shared__ float sqs[2][KC][BT];

    // linear -> lower-triangle (bi >= bj)
    int t = blockIdx.x;
    int bi = (int)((sqrtf(8.0f * (float)t + 1.0f) - 1.0f) * 0.5f);
    while ((bi + 1) * (bi + 2) / 2 <= t) ++bi;
    while (bi * (bi + 1) / 2 > t) --bi;
    int bj = t - bi * (bi + 1) / 2;

    const int i0 = bi * BT;
    const int j0 = bj * BT;
    const int tid = threadIdx.x;
    const int tx = tid & 15;       // j-cols tx*8..+7
    const int ty = tid >> 4;       // i-rows ty*8..+7

    unsigned fail0 = 0u, fail1 = 0u;   // bit u*8+v (u<4) / (u-4)*8+v

    for (int kp = 0; kp < NPH; ++kp) {
        __syncthreads();
        // ---- stage: 2048 float4 loads, 8/thread; each covers 4 rows ----
#pragma unroll
        for (int l = 0; l < 8; ++l) {
            int gid = l * 256 + tid;
            int side = gid >> 10;
            int q = gid & 1023;            // m4(4) | r(4) | kl(1) | g(1)
            int g = q & 1;
            int kl = (q >> 1) & 1;
            int r = (q >> 2) & 15;
            int m4 = q >> 6;
            int k = kp * KC + kl;
            int bt = side ? bj : bi;
            int h = m4 * 64 + (r >> 2) * 16 + (bt >> 1);
            int w0 = (r & 3) * 256 + k * 16 + 8 * (bt & 1) + 4 * g;
            float4 v = *(const float4*)&x[h * 1024 + w0];
            int c = (kl << 2) | (r >> 2);
            int e = r & 3;
            float* Sb = side ? (float*)Sj : (float*)Si;
#pragma unroll
            for (int dd = 0; dd < 4; ++dd) {   // elem dd -> row (4g+dd)*16+m4
                float val = (dd == 0) ? v.x : (dd == 1) ? v.y : (dd == 2) ? v.z : v.w;
                int row = (4 * g + dd) * 16 + m4;
                int ch = c ^ swzrow(row);
                Sb[(row * RSTRIDE + ch) * 4 + e] = val;
            }
        }
        __syncthreads();
        // ---- per-column sq: plain adds, r ascending (2 values/thread) ----
#pragma unroll
        for (int s = 0; s < 2; ++s) {
            int idx = s * 256 + tid;
            int side = idx >> 8;
            int kl = (idx >> 7) & 1;
            int row = idx & 127;
            const float4* Sb = (side ? Sj : Si) + row * RSTRIDE;
            int swz = swzrow(row);
            float acc;
            {
                float4 v = Sb[(kl * 4) ^ swz];
                acc = v.x * v.x;
                float t1 = v.y * v.y; acc = acc + t1;
                float t2 = v.z * v.z; acc = acc + t2;
                float t3 = v.w * v.w; acc = acc + t3;
            }
#pragma unroll
            for (int rc = 1; rc < 4; ++rc) {
                float4 v = Sb[(kl * 4 + rc) ^ swz];
                float t0 = v.x * v.x; acc = acc + t0;
                float t1 = v.y * v.y; acc = acc + t1;
                float t2 = v.z * v.z; acc = acc + t2;
                float t3 = v.w * v.w; acc = acc + t3;
            }
            sqs[side][kl][row] = acc;
        }
        __syncthreads();
        // ---- compute: 8x8 cells via named float4 accumulators ----
#pragma unroll
        for (int kl = 0; kl < KC; ++kl) {
            float4 d0A = {0.f, 0.f, 0.f, 0.f}, d0B = {0.f, 0.f, 0.f, 0.f};
            float4 d1A = {0.f, 0.f, 0.f, 0.f}, d1B = {0.f, 0.f, 0.f, 0.f};
            float4 d2A = {0.f, 0.f, 0.f, 0.f}, d2B = {0.f, 0.f, 0.f, 0.f};
            float4 d3A = {0.f, 0.f, 0.f, 0.f}, d3B = {0.f, 0.f, 0.f, 0.f};
            float4 d4A = {0.f, 0.f, 0.f, 0.f}, d4B = {0.f, 0.f, 0.f, 0.f};
            float4 d5A = {0.f, 0.f, 0.f, 0.f}, d5B = {0.f, 0.f, 0.f, 0.f};
            float4 d6A = {0.f, 0.f, 0.f, 0.f}, d6B = {0.f, 0.f, 0.f, 0.f};
            float4 d7A = {0.f, 0.f, 0.f, 0.f}, d7B = {0.f, 0.f, 0.f, 0.f};
#pragma unroll
            for (int rc = 0; rc < 4; ++rc) {
                const int c = kl * 4 + rc;
                LDA(0) LDA(1) LDA(2) LDA(3) LDA(4) LDA(5) LDA(6) LDA(7)
                COL(0, A.x)
                COL(1, A.y)
                COL(2, A.z)
                COL(3, A.w)
                COL(4, B.x)
                COL(5, B.y)
                COL(6, B.z)
                COL(7, B.w)
            }
            const float4 si0 = *(const float4*)&sqs[0][kl][ty * 8];
            const float4 si1 = *(const float4*)&sqs[0][kl][ty * 8 + 4];
            const float4 sj0 = *(const float4*)&sqs[1][kl][tx * 8];
            const float4 sj1 = *(const float4*)&sqs[1][kl][tx * 8 + 4];
            EPIROW(0, si0.x, fail0, 0)
            EPIROW(1, si0.y, fail0, 8)
            EPIROW(2, si0.z, fail0, 16)
            EPIROW(3, si0.w, fail0, 24)
            EPIROW(4, si1.x, fail1, 0)
            EPIROW(5, si1.y, fail1, 8)
            EPIROW(6, si1.z, fail1, 16)
            EPIROW(7, si1.w, fail1, 24)
        }
    }

    // ---- stores: direct + mirrored (A exactly symmetric) ----
#pragma unroll
    for (int u = 0; u < 8; ++u) {
        unsigned m8 = ((u < 4) ? (fail0 >> (u * 8)) : (fail1 >> ((u - 4) * 8))) & 0xffu;
        float4 o0, o1;
        o0.x = (m8 & 1u)   ? 0.0f : 1.0f;
        o0.y = (m8 & 2u)   ? 0.0f : 1.0f;
        o0.z = (m8 & 4u)   ? 0.0f : 1.0f;
        o0.w = (m8 & 8u)   ? 0.0f : 1.0f;
        o1.x = (m8 & 16u)  ? 0.0f : 1.0f;
        o1.y = (m8 & 32u)  ? 0.0f : 1.0f;
        o1.z = (m8 & 64u)  ? 0.0f : 1.0f;
        o1.w = (m8 & 128u) ? 0.0f : 1.0f;
        size_t base = (size_t)(i0 + ty * 8 + u) * NPATCH + j0 + tx * 8;
        *(float4*)&A[base] = o0;
        *(float4*)&A[base + 4] = o1;
    }
    if (bi != bj) {
#pragma unroll
        for (int v = 0; v < 8; ++v) {
            float4 o0, o1;
            o0.x = ((fail0 >> (0 * 8 + v)) & 1u) ? 0.0f : 1.0f;
            o0.y = ((fail0 >> (1 * 8 + v)) & 1u) ? 0.0f : 1.0f;
            o0.z = ((fail0 >> (2 * 8 + v)) & 1u) ? 0.0f : 1.0f;
            o0.w = ((fail0 >> (3 * 8 + v)) & 1u) ? 0.0f : 1.0f;
            o1.x = ((fail1 >> (0 * 8 + v)) & 1u) ? 0.0f : 1.0f;
            o1.y = ((fail1 >> (1 * 8 + v)) & 1u) ? 0.0f : 1.0f;
            o1.z = ((fail1 >> (2 * 8 + v)) & 1u) ? 0.0f : 1.0f;
            o1.w = ((fail1 >> (3 * 8 + v)) & 1u) ? 0.0f : 1.0f;
            size_t base = (size_t)(j0 + tx * 8 + v) * NPATCH + i0 + ty * 8;
            *(float4*)&A[base] = o0;
            *(float4*)&A[base + 4] = o1;
        }
    }
}

extern "C" void kernel_launch(void* const* d_in, const int* in_sizes, int n_in,
                              void* d_out, int out_size, void* d_ws, size_t ws_size,
                              hipStream_t stream) {
    const float* x = (const float*)d_in[0];
    float* A = (float*)d_out;
    (void)d_ws; (void)ws_size;

    const int nblk = NT * (NT + 1) / 2;  // 528
    adj_kernel<<<nblk, 256, 0, stream>>>(x, A);
}

// Round 4
// 242.103 us; speedup vs baseline: 4.9597x; 2.5321x over previous
//
#include <hip/hip_runtime.h>

// GraphConstruction: x[1,1024,1024] fp32 -> A[4096,4096] in {0,1} fp32.
// patches[n,r,k] = x[h,w], h = (n&15)*64 + (r>>2)*16 + (n>>8),
//                          w = (r&3)*256 + k*16 + ((n>>4)&15)
// LOCKED NUMERICS (R6..R16, absmax 0):
//   sq[n,k]: acc = p0^2; acc = acc + fl(p_r^2), r ascending (plain adds)
//   G: acc = fmaf(a_r, b_r, acc), r ascending;  d2 = fmaf(-2,G,fl(si+sj))
//   decision: all_k (d2 <= 49.0f) == !any_k (d2 > 49.0f) -> per-cell FAIL
//   BIT instead of running fp max. A bit-exactly symmetric -> mirror stores.
// R17 = R16 (128x128 block, 8x8/thread, named float4 accumulators) with
//   amdgpu_waves_per_eu(1,1) instead of (2,2).
//   Budget ladder evidence: no attr -> VGPR 84 (=512/6, 6 w/EU target);
//   (2,2) -> VGPR 128 (=512/4, backend clamped to the LDS-derived 4-blk/CU
//   cap, NOT the requested 2). Live set ~140-150 -> ~18 regs spill in the
//   rc loop -> 628 MB scratch (WRITE 694 MB vs 66 MB output), VALUBusy 13%,
//   562us. (1,1) -> budget 512 -> allocator takes ~160-200, zero spill.
//   Occupancy cost is nil: grid 528 = 2.06 blocks/CU; even at 200 VGPR the
//   HW runs 2 blocks/CU. Diagnostic: VGPR_Count must jump >=160 and
//   WRITE_SIZE collapse to ~66 MB; else pivot (amdgpu_num_vgpr / 8x4 tile).
//   LDS economics: 1.0 B/FMA (half of R13) -> ~50us LDS floor; FMA floor
//   27.7us; predicted 65-90us.

#define NPATCH 4096
#define BT 128
#define NT (NPATCH / BT)   // 32 -> 528 lower-triangle blocks
#define NPH 8
#define KC 2
#define RSTRIDE 9          // float4 per row (8 data chunks + 1 pad)

__device__ __forceinline__ int swzrow(int row) {
    return ((row >> 2) + (row >> 5)) & 7;
}

// d{u}A holds cols v=0..3, d{u}B cols v=4..7; chain = fmaf r ascending.
#define FMA4(dst, av, bv)              \
    dst = fmaf(av.x, bv.x, dst);       \
    dst = fmaf(av.y, bv.y, dst);       \
    dst = fmaf(av.z, bv.z, dst);       \
    dst = fmaf(av.w, bv.w, dst);

#define LDA(u)                                                                 \
    const float4 a##u = Si[(ty * 8 + u) * RSTRIDE +                            \
                           (c ^ ((((ty * 8 + u) >> 2) + ((ty * 8 + u) >> 5)) & 7))];

#define COL(v, comp)                                                           \
    {                                                                          \
        const int row_ = tx * 8 + v;                                           \
        const float4 b_ =                                                      \
            Sj[row_ * RSTRIDE + (c ^ (((row_ >> 2) + (row_ >> 5)) & 7))];      \
        FMA4(d0##comp, a0, b_)                                                 \
        FMA4(d1##comp, a1, b_)                                                 \
        FMA4(d2##comp, a2, b_)                                                 \
        FMA4(d3##comp, a3, b_)                                                 \
        FMA4(d4##comp, a4, b_)                                                 \
        FMA4(d5##comp, a5, b_)                                                 \
        FMA4(d6##comp, a6, b_)                                                 \
        FMA4(d7##comp, a7, b_)                                                 \
    }

#define CELL(dcomp, siv, sjv, fw, bit)                                         \
    {                                                                          \
        const float s_ = (siv) + (sjv);          /* fl(si+sj) */               \
        const float d2_ = fmaf(-2.0f, dcomp, s_); /* fl(s-2G) */               \
        fw |= (d2_ > 49.0f ? 1u : 0u) << (bit);                                \
    }

#define EPIROW(u, siv, fw, base)                                               \
    CELL(d##u##A.x, siv, sj0.x, fw, (base) + 0)                                \
    CELL(d##u##A.y, siv, sj0.y, fw, (base) + 1)                                \
    CELL(d##u##A.z, siv, sj0.z, fw, (base) + 2)                                \
    CELL(d##u##A.w, siv, sj0.w, fw, (base) + 3)                                \
    CELL(d##u##B.x, siv, sj1.x, fw, (base) + 4)                                \
    CELL(d##u##B.y, siv, sj1.y, fw, (base) + 5)                                \
    CELL(d##u##B.z, siv, sj1.z, fw, (base) + 6)                                \
    CELL(d##u##B.w, siv, sj1.w, fw, (base) + 7)

__global__ __launch_bounds__(256)
__attribute__((amdgpu_waves_per_eu(1, 1)))
void adj_kernel(const float* __restrict__ x, float* __restrict__ A) {
#pragma clang fp contract(off)
    __shared__ float4 Si[BT * RSTRIDE];
    __shared__ float4 Sj[BT * RSTRIDE];
    __shared__ float sqs[2][KC][BT];

    // linear -> lower-triangle (bi >= bj)
    int t = blockIdx.x;
    int bi = (int)((sqrtf(8.0f * (float)t + 1.0f) - 1.0f) * 0.5f);
    while ((bi + 1) * (bi + 2) / 2 <= t) ++bi;
    while (bi * (bi + 1) / 2 > t) --bi;
    int bj = t - bi * (bi + 1) / 2;

    const int i0 = bi * BT;
    const int j0 = bj * BT;
    const int tid = threadIdx.x;
    const int tx = tid & 15;       // j-cols tx*8..+7
    const int ty = tid >> 4;       // i-rows ty*8..+7

    unsigned fail0 = 0u, fail1 = 0u;   // bit u*8+v (u<4) / (u-4)*8+v

    for (int kp = 0; kp < NPH; ++kp) {
        __syncthreads();
        // ---- stage: 2048 float4 loads, 8/thread; each covers 4 rows ----
#pragma unroll
        for (int l = 0; l < 8; ++l) {
            int gid = l * 256 + tid;
            int side = gid >> 10;
            int q = gid & 1023;            // m4(4) | r(4) | kl(1) | g(1)
            int g = q & 1;
            int kl = (q >> 1) & 1;
            int r = (q >> 2) & 15;
            int m4 = q >> 6;
            int k = kp * KC + kl;
            int bt = side ? bj : bi;
            int h = m4 * 64 + (r >> 2) * 16 + (bt >> 1);
            int w0 = (r & 3) * 256 + k * 16 + 8 * (bt & 1) + 4 * g;
            float4 v = *(const float4*)&x[h * 1024 + w0];
            int c = (kl << 2) | (r >> 2);
            int e = r & 3;
            float* Sb = side ? (float*)Sj : (float*)Si;
#pragma unroll
            for (int dd = 0; dd < 4; ++dd) {   // elem dd -> row (4g+dd)*16+m4
                float val = (dd == 0) ? v.x : (dd == 1) ? v.y : (dd == 2) ? v.z : v.w;
                int row = (4 * g + dd) * 16 + m4;
                int ch = c ^ swzrow(row);
                Sb[(row * RSTRIDE + ch) * 4 + e] = val;
            }
        }
        __syncthreads();
        // ---- per-column sq: plain adds, r ascending (2 values/thread) ----
#pragma unroll
        for (int s = 0; s < 2; ++s) {
            int idx = s * 256 + tid;
            int side = idx >> 8;
            int kl = (idx >> 7) & 1;
            int row = idx & 127;
            const float4* Sb = (side ? Sj : Si) + row * RSTRIDE;
            int swz = swzrow(row);
            float acc;
            {
                float4 v = Sb[(kl * 4) ^ swz];
                acc = v.x * v.x;
                float t1 = v.y * v.y; acc = acc + t1;
                float t2 = v.z * v.z; acc = acc + t2;
                float t3 = v.w * v.w; acc = acc + t3;
            }
#pragma unroll
            for (int rc = 1; rc < 4; ++rc) {
                float4 v = Sb[(kl * 4 + rc) ^ swz];
                float t0 = v.x * v.x; acc = acc + t0;
                float t1 = v.y * v.y; acc = acc + t1;
                float t2 = v.z * v.z; acc = acc + t2;
                float t3 = v.w * v.w; acc = acc + t3;
            }
            sqs[side][kl][row] = acc;
        }
        __syncthreads();
        // ---- compute: 8x8 cells via named float4 accumulators ----
#pragma unroll
        for (int kl = 0; kl < KC; ++kl) {
            float4 d0A = {0.f, 0.f, 0.f, 0.f}, d0B = {0.f, 0.f, 0.f, 0.f};
            float4 d1A = {0.f, 0.f, 0.f, 0.f}, d1B = {0.f, 0.f, 0.f, 0.f};
            float4 d2A = {0.f, 0.f, 0.f, 0.f}, d2B = {0.f, 0.f, 0.f, 0.f};
            float4 d3A = {0.f, 0.f, 0.f, 0.f}, d3B = {0.f, 0.f, 0.f, 0.f};
            float4 d4A = {0.f, 0.f, 0.f, 0.f}, d4B = {0.f, 0.f, 0.f, 0.f};
            float4 d5A = {0.f, 0.f, 0.f, 0.f}, d5B = {0.f, 0.f, 0.f, 0.f};
            float4 d6A = {0.f, 0.f, 0.f, 0.f}, d6B = {0.f, 0.f, 0.f, 0.f};
            float4 d7A = {0.f, 0.f, 0.f, 0.f}, d7B = {0.f, 0.f, 0.f, 0.f};
#pragma unroll
            for (int rc = 0; rc < 4; ++rc) {
                const int c = kl * 4 + rc;
                LDA(0) LDA(1) LDA(2) LDA(3) LDA(4) LDA(5) LDA(6) LDA(7)
                COL(0, A.x)
                COL(1, A.y)
                COL(2, A.z)
                COL(3, A.w)
                COL(4, B.x)
                COL(5, B.y)
                COL(6, B.z)
                COL(7, B.w)
            }
            const float4 si0 = *(const float4*)&sqs[0][kl][ty * 8];
            const float4 si1 = *(const float4*)&sqs[0][kl][ty * 8 + 4];
            const float4 sj0 = *(const float4*)&sqs[1][kl][tx * 8];
            const float4 sj1 = *(const float4*)&sqs[1][kl][tx * 8 + 4];
            EPIROW(0, si0.x, fail0, 0)
            EPIROW(1, si0.y, fail0, 8)
            EPIROW(2, si0.z, fail0, 16)
            EPIROW(3, si0.w, fail0, 24)
            EPIROW(4, si1.x, fail1, 0)
            EPIROW(5, si1.y, fail1, 8)
            EPIROW(6, si1.z, fail1, 16)
            EPIROW(7, si1.w, fail1, 24)
        }
    }

    // ---- stores: direct + mirrored (A exactly symmetric) ----
#pragma unroll
    for (int u = 0; u < 8; ++u) {
        unsigned m8 = ((u < 4) ? (fail0 >> (u * 8)) : (fail1 >> ((u - 4) * 8))) & 0xffu;
        float4 o0, o1;
        o0.x = (m8 & 1u)   ? 0.0f : 1.0f;
        o0.y = (m8 & 2u)   ? 0.0f : 1.0f;
        o0.z = (m8 & 4u)   ? 0.0f : 1.0f;
        o0.w = (m8 & 8u)   ? 0.0f : 1.0f;
        o1.x = (m8 & 16u)  ? 0.0f : 1.0f;
        o1.y = (m8 & 32u)  ? 0.0f : 1.0f;
        o1.z = (m8 & 64u)  ? 0.0f : 1.0f;
        o1.w = (m8 & 128u) ? 0.0f : 1.0f;
        size_t base = (size_t)(i0 + ty * 8 + u) * NPATCH + j0 + tx * 8;
        *(float4*)&A[base] = o0;
        *(float4*)&A[base + 4] = o1;
    }
    if (bi != bj) {
#pragma unroll
        for (int v = 0; v < 8; ++v) {
            float4 o0, o1;
            o0.x = ((fail0 >> (0 * 8 + v)) & 1u) ? 0.0f : 1.0f;
            o0.y = ((fail0 >> (1 * 8 + v)) & 1u) ? 0.0f : 1.0f;
            o0.z = ((fail0 >> (2 * 8 + v)) & 1u) ? 0.0f : 1.0f;
            o0.w = ((fail0 >> (3 * 8 + v)) & 1u) ? 0.0f : 1.0f;
            o1.x = ((fail1 >> (0 * 8 + v)) & 1u) ? 0.0f : 1.0f;
            o1.y = ((fail1 >> (1 * 8 + v)) & 1u) ? 0.0f : 1.0f;
            o1.z = ((fail1 >> (2 * 8 + v)) & 1u) ? 0.0f : 1.0f;
            o1.w = ((fail1 >> (3 * 8 + v)) & 1u) ? 0.0f : 1.0f;
            size_t base = (size_t)(j0 + tx * 8 + v) * NPATCH + i0 + ty * 8;
            *(float4*)&A[base] = o0;
            *(float4*)&A[base + 4] = o1;
        }
    }
}

extern "C" void kernel_launch(void* const* d_in, const int* in_sizes, int n_in,
                              void* d_out, int out_size, void* d_ws, size_t ws_size,
                              hipStream_t stream) {
    const float* x = (const float*)d_in[0];
    float* A = (float*)d_out;
    (void)d_ws; (void)ws_size;

    const int nblk = NT * (NT + 1) / 2;  // 528
    adj_kernel<<<nblk, 256, 0, stream>>>(x, A);
}

// Round 5
// 236.816 us; speedup vs baseline: 5.0704x; 1.0223x over previous
//
#include <hip/hip_runtime.h>

// GraphConstruction: x[1,1024,1024] fp32 -> A[4096,4096] in {0,1} fp32.
// patches[n,r,k] = x[h,w], h = (n&15)*64 + (r>>2)*16 + (n>>8),
//                          w = (r&3)*256 + k*16 + ((n>>4)&15)
// LOCKED NUMERICS (R6..R17, absmax 0):
//   sq[n,k]: acc = p0^2; acc = acc + fl(p_r^2), r ascending (plain adds)
//   G: acc = fmaf(a_r, b_r, acc), r ascending;  d2 = fmaf(-2,G,fl(si+sj))
//   decision: all_k (d2 <= 49.0f) == !any_k (d2 > 49.0f) -> per-cell FAIL
//   BIT instead of running fp max. A bit-exactly symmetric -> mirror stores.
// R18 = R17 (128x128 block, 8x8/thread, named float4 accumulators) with
//   amdgpu_waves_per_eu(1, 2) instead of (1,1).
//   VGPR-budget ladder (measured): no attr -> 84 (=512/6 target, spills);
//   (2,2) -> 128 (=512/4, spills); (1,1) -> 200, ZERO spill (WRITE 65.5MB
//   = pure output) — but (1,1) also capped RUNTIME occupancy at 1 wave/EU
//   -> OccupancyPercent 8%, VALUBusy 41%, no latency hiding, 193us.
//   (1,2): min=1 keeps the 512 budget (no re-spill incentive), max=2 lets
//   HW run 2 waves/SIMD (200x2=400<=512 regs OK; LDS 38.9KB allows 4
//   blocks/CU; grid 528 = 2.06 blocks/CU). Expect VALUBusy ~70%,
//   dur ~95-120us. Known ceiling: VALU-issue-bound at ~76-79us busy time
//   (R13 and R17 agree); if R18 ties R13 (~105us), next lever is VALU
//   instruction count (epilogue/addressing), not memory.

#define NPATCH 4096
#define BT 128
#define NT (NPATCH / BT)   // 32 -> 528 lower-triangle blocks
#define NPH 8
#define KC 2
#define RSTRIDE 9          // float4 per row (8 data chunks + 1 pad)

__device__ __forceinline__ int swzrow(int row) {
    return ((row >> 2) + (row >> 5)) & 7;
}

// d{u}A holds cols v=0..3, d{u}B cols v=4..7; chain = fmaf r ascending.
#define FMA4(dst, av, bv)              \
    dst = fmaf(av.x, bv.x, dst);       \
    dst = fmaf(av.y, bv.y, dst);       \
    dst = fmaf(av.z, bv.z, dst);       \
    dst = fmaf(av.w, bv.w, dst);

#define LDA(u)                                                                 \
    const float4 a##u = Si[(ty * 8 + u) * RSTRIDE +                            \
                           (c ^ ((((ty * 8 + u) >> 2) + ((ty * 8 + u) >> 5)) & 7))];

#define COL(v, comp)                                                           \
    {                                                                          \
        const int row_ = tx * 8 + v;                                           \
        const float4 b_ =                                                      \
            Sj[row_ * RSTRIDE + (c ^ (((row_ >> 2) + (row_ >> 5)) & 7))];      \
        FMA4(d0##comp, a0, b_)                                                 \
        FMA4(d1##comp, a1, b_)                                                 \
        FMA4(d2##comp, a2, b_)                                                 \
        FMA4(d3##comp, a3, b_)                                                 \
        FMA4(d4##comp, a4, b_)                                                 \
        FMA4(d5##comp, a5, b_)                                                 \
        FMA4(d6##comp, a6, b_)                                                 \
        FMA4(d7##comp, a7, b_)                                                 \
    }

#define CELL(dcomp, siv, sjv, fw, bit)                                         \
    {                                                                          \
        const float s_ = (siv) + (sjv);          /* fl(si+sj) */               \
        const float d2_ = fmaf(-2.0f, dcomp, s_); /* fl(s-2G) */               \
        fw |= (d2_ > 49.0f ? 1u : 0u) << (bit);                                \
    }

#define EPIROW(u, siv, fw, base)                                               \
    CELL(d##u##A.x, siv, sj0.x, fw, (base) + 0)                                \
    CELL(d##u##A.y, siv, sj0.y, fw, (base) + 1)                                \
    CELL(d##u##A.z, siv, sj0.z, fw, (base) + 2)                                \
    CELL(d##u##A.w, siv, sj0.w, fw, (base) + 3)                                \
    CELL(d##u##B.x, siv, sj1.x, fw, (base) + 4)                                \
    CELL(d##u##B.y, siv, sj1.y, fw, (base) + 5)                                \
    CELL(d##u##B.z, siv, sj1.z, fw, (base) + 6)                                \
    CELL(d##u##B.w, siv, sj1.w, fw, (base) + 7)

__global__ __launch_bounds__(256)
__attribute__((amdgpu_waves_per_eu(1, 2)))
void adj_kernel(const float* __restrict__ x, float* __restrict__ A) {
#pragma clang fp contract(off)
    __shared__ float4 Si[BT * RSTRIDE];
    __shared__ float4 Sj[BT * RSTRIDE];
    __shared__ float sqs[2][KC][BT];

    // linear -> lower-triangle (bi >= bj)
    int t = blockIdx.x;
    int bi = (int)((sqrtf(8.0f * (float)t + 1.0f) - 1.0f) * 0.5f);
    while ((bi + 1) * (bi + 2) / 2 <= t) ++bi;
    while (bi * (bi + 1) / 2 > t) --bi;
    int bj = t - bi * (bi + 1) / 2;

    const int i0 = bi * BT;
    const int j0 = bj * BT;
    const int tid = threadIdx.x;
    const int tx = tid & 15;       // j-cols tx*8..+7
    const int ty = tid >> 4;       // i-rows ty*8..+7

    unsigned fail0 = 0u, fail1 = 0u;   // bit u*8+v (u<4) / (u-4)*8+v

    for (int kp = 0; kp < NPH; ++kp) {
        __syncthreads();
        // ---- stage: 2048 float4 loads, 8/thread; each covers 4 rows ----
#pragma unroll
        for (int l = 0; l < 8; ++l) {
            int gid = l * 256 + tid;
            int side = gid >> 10;
            int q = gid & 1023;            // m4(4) | r(4) | kl(1) | g(1)
            int g = q & 1;
            int kl = (q >> 1) & 1;
            int r = (q >> 2) & 15;
            int m4 = q >> 6;
            int k = kp * KC + kl;
            int bt = side ? bj : bi;
            int h = m4 * 64 + (r >> 2) * 16 + (bt >> 1);
            int w0 = (r & 3) * 256 + k * 16 + 8 * (bt & 1) + 4 * g;
            float4 v = *(const float4*)&x[h * 1024 + w0];
            int c = (kl << 2) | (r >> 2);
            int e = r & 3;
            float* Sb = side ? (float*)Sj : (float*)Si;
#pragma unroll
            for (int dd = 0; dd < 4; ++dd) {   // elem dd -> row (4g+dd)*16+m4
                float val = (dd == 0) ? v.x : (dd == 1) ? v.y : (dd == 2) ? v.z : v.w;
                int row = (4 * g + dd) * 16 + m4;
                int ch = c ^ swzrow(row);
                Sb[(row * RSTRIDE + ch) * 4 + e] = val;
            }
        }
        __syncthreads();
        // ---- per-column sq: plain adds, r ascending (2 values/thread) ----
#pragma unroll
        for (int s = 0; s < 2; ++s) {
            int idx = s * 256 + tid;
            int side = idx >> 8;
            int kl = (idx >> 7) & 1;
            int row = idx & 127;
            const float4* Sb = (side ? Sj : Si) + row * RSTRIDE;
            int swz = swzrow(row);
            float acc;
            {
                float4 v = Sb[(kl * 4) ^ swz];
                acc = v.x * v.x;
                float t1 = v.y * v.y; acc = acc + t1;
                float t2 = v.z * v.z; acc = acc + t2;
                float t3 = v.w * v.w; acc = acc + t3;
            }
#pragma unroll
            for (int rc = 1; rc < 4; ++rc) {
                float4 v = Sb[(kl * 4 + rc) ^ swz];
                float t0 = v.x * v.x; acc = acc + t0;
                float t1 = v.y * v.y; acc = acc + t1;
                float t2 = v.z * v.z; acc = acc + t2;
                float t3 = v.w * v.w; acc = acc + t3;
            }
            sqs[side][kl][row] = acc;
        }
        __syncthreads();
        // ---- compute: 8x8 cells via named float4 accumulators ----
#pragma unroll
        for (int kl = 0; kl < KC; ++kl) {
            float4 d0A = {0.f, 0.f, 0.f, 0.f}, d0B = {0.f, 0.f, 0.f, 0.f};
            float4 d1A = {0.f, 0.f, 0.f, 0.f}, d1B = {0.f, 0.f, 0.f, 0.f};
            float4 d2A = {0.f, 0.f, 0.f, 0.f}, d2B = {0.f, 0.f, 0.f, 0.f};
            float4 d3A = {0.f, 0.f, 0.f, 0.f}, d3B = {0.f, 0.f, 0.f, 0.f};
            float4 d4A = {0.f, 0.f, 0.f, 0.f}, d4B = {0.f, 0.f, 0.f, 0.f};
            float4 d5A = {0.f, 0.f, 0.f, 0.f}, d5B = {0.f, 0.f, 0.f, 0.f};
            float4 d6A = {0.f, 0.f, 0.f, 0.f}, d6B = {0.f, 0.f, 0.f, 0.f};
            float4 d7A = {0.f, 0.f, 0.f, 0.f}, d7B = {0.f, 0.f, 0.f, 0.f};
#pragma unroll
            for (int rc = 0; rc < 4; ++rc) {
                const int c = kl * 4 + rc;
                LDA(0) LDA(1) LDA(2) LDA(3) LDA(4) LDA(5) LDA(6) LDA(7)
                COL(0, A.x)
                COL(1, A.y)
                COL(2, A.z)
                COL(3, A.w)
                COL(4, B.x)
                COL(5, B.y)
                COL(6, B.z)
                COL(7, B.w)
            }
            const float4 si0 = *(const float4*)&sqs[0][kl][ty * 8];
            const float4 si1 = *(const float4*)&sqs[0][kl][ty * 8 + 4];
            const float4 sj0 = *(const float4*)&sqs[1][kl][tx * 8];
            const float4 sj1 = *(const float4*)&sqs[1][kl][tx * 8 + 4];
            EPIROW(0, si0.x, fail0, 0)
            EPIROW(1, si0.y, fail0, 8)
            EPIROW(2, si0.z, fail0, 16)
            EPIROW(3, si0.w, fail0, 24)
            EPIROW(4, si1.x, fail1, 0)
            EPIROW(5, si1.y, fail1, 8)
            EPIROW(6, si1.z, fail1, 16)
            EPIROW(7, si1.w, fail1, 24)
        }
    }

    // ---- stores: direct + mirrored (A exactly symmetric) ----
#pragma unroll
    for (int u = 0; u < 8; ++u) {
        unsigned m8 = ((u < 4) ? (fail0 >> (u * 8)) : (fail1 >> ((u - 4) * 8))) & 0xffu;
        float4 o0, o1;
        o0.x = (m8 & 1u)   ? 0.0f : 1.0f;
        o0.y = (m8 & 2u)   ? 0.0f : 1.0f;
        o0.z = (m8 & 4u)   ? 0.0f : 1.0f;
        o0.w = (m8 & 8u)   ? 0.0f : 1.0f;
        o1.x = (m8 & 16u)  ? 0.0f : 1.0f;
        o1.y = (m8 & 32u)  ? 0.0f : 1.0f;
        o1.z = (m8 & 64u)  ? 0.0f : 1.0f;
        o1.w = (m8 & 128u) ? 0.0f : 1.0f;
        size_t base = (size_t)(i0 + ty * 8 + u) * NPATCH + j0 + tx * 8;
        *(float4*)&A[base] = o0;
        *(float4*)&A[base + 4] = o1;
    }
    if (bi != bj) {
#pragma unroll
        for (int v = 0; v < 8; ++v) {
            float4 o0, o1;
            o0.x = ((fail0 >> (0 * 8 + v)) & 1u) ? 0.0f : 1.0f;
            o0.y = ((fail0 >> (1 * 8 + v)) & 1u) ? 0.0f : 1.0f;
            o0.z = ((fail0 >> (2 * 8 + v)) & 1u) ? 0.0f : 1.0f;
            o0.w = ((fail0 >> (3 * 8 + v)) & 1u) ? 0.0f : 1.0f;
            o1.x = ((fail1 >> (0 * 8 + v)) & 1u) ? 0.0f : 1.0f;
            o1.y = ((fail1 >> (1 * 8 + v)) & 1u) ? 0.0f : 1.0f;
            o1.z = ((fail1 >> (2 * 8 + v)) & 1u) ? 0.0f : 1.0f;
            o1.w = ((fail1 >> (3 * 8 + v)) & 1u) ? 0.0f : 1.0f;
            size_t base = (size_t)(j0 + tx * 8 + v) * NPATCH + i0 + ty * 8;
            *(float4*)&A[base] = o0;
            *(float4*)&A[base + 4] = o1;
        }
    }
}

extern "C" void kernel_launch(void* const* d_in, const int* in_sizes, int n_in,
                              void* d_out, int out_size, void* d_ws, size_t ws_size,
                              hipStream_t stream) {
    const float* x = (const float*)d_in[0];
    float* A = (float*)d_out;
    (void)d_ws; (void)ws_size;

    const int nblk = NT * (NT + 1) / 2;  // 528
    adj_kernel<<<nblk, 256, 0, stream>>>(x, A);
}